// Round 12
// baseline (1272.606 us; speedup 1.0000x reference)
//
#include <hip/hip_runtime.h>
#include <hip/hip_bf16.h>
#include <math.h>

#define B_    4
#define GRID_ 12
#define DM_   384
#define DEPTH_ 8
#define L_    1728      // 12^3
#define DI_   768
#define NS_   16
#define DC_   4
#define DTR_  24
#define KEEP_ 432
#define XPR_  56        // DTR + 2*NS
#define NC_   48        // scan chunks (48*9 = 432) — R7/R10-proven numerics
#define CL_   9         // steps per chunk; do NOT grow without exact exps
#define XSPLIT_ 8       // x_proj split-K slabs (R12: 4->8 for occupancy)

// LESSON (R8/R9/R11, all failed bit-identically): do NOT pass data between
// blocks through grid.sync() with plain loads/stores on gfx950 — per-XCD L2
// non-coherence serves stale values deterministically. Kernel boundaries are
// the reliable visibility fence; the scan stays as 3 separate dispatches.

typedef __attribute__((ext_vector_type(8))) short short8;
typedef __attribute__((ext_vector_type(4))) float floatx4;

// ---------------------------------------------------------------- utilities
__device__ __forceinline__ float silu_f(float x) {
    return x / (1.0f + __expf(-x));
}
__device__ __forceinline__ float softplus_f(float x) {
    return (x > 20.0f) ? x : __logf(1.0f + __expf(x));
}
__device__ __forceinline__ float gelu_exact_f(float x) {
    return 0.5f * x * (1.0f + erff(x * 0.7071067811865476f));
}
__device__ __forceinline__ unsigned short f2bf(float x) {
    union { float f; unsigned int u; } c; c.f = x;
    unsigned int u = c.u;
    unsigned int r = (u + 0x7fffu + ((u >> 16) & 1u)) >> 16;
    return (unsigned short)r;
}
// async global->LDS, 16B per lane; LDS dest is wave-uniform base, HW writes
// lane i at base + i*16 — lane-linear layout required.
__device__ __forceinline__ void gld_lds16(const unsigned short* g, unsigned short* l) {
    __builtin_amdgcn_global_load_lds(
        (const __attribute__((address_space(1))) void*)g,
        (__attribute__((address_space(3))) void*)l, 16, 0, 0);
}

// ---------------------------------------------------------------- weight cast
#define S0_ (DEPTH_ * 2 * DI_ * DM_)   // inW
#define S1_ (DEPTH_ * XPR_ * DI_)      // xpw
#define S3_ (DEPTH_ * DM_ * DI_)       // ow
#define S4_ (DEPTH_ * 2 * DM_ * DM_)   // f1w
#define S5_ (DEPTH_ * DM_ * 2 * DM_)   // f2w
#define WTOT_ (S0_ + S1_ + S3_ + S4_ + S5_)

__global__ void cast_weights_k(const float* __restrict__ w0,
                               const float* __restrict__ w1,
                               const float* __restrict__ w3,
                               const float* __restrict__ w4,
                               const float* __restrict__ w5,
                               unsigned short* __restrict__ out) {
    int i = blockIdx.x * 256 + threadIdx.x;
    if (i >= WTOT_) return;
    float v;
    if (i < S0_) v = w0[i];
    else if (i < S0_ + S1_) v = w1[i - S0_];
    else if (i < S0_ + S1_ + S3_) v = w3[i - S0_ - S1_];
    else if (i < S0_ + S1_ + S3_ + S4_) v = w4[i - S0_ - S1_ - S3_];
    else v = w5[i - S0_ - S1_ - S3_ - S4_];
    out[i] = f2bf(v);
}

// ---------------------------------------------------------------- ids / rank
__global__ __launch_bounds__(256) void compute_ids_k(
        const int* __restrict__ active,
        int* __restrict__ RANK, int* __restrict__ IDS) {
    __shared__ int cnt[256];
    int b = blockIdx.x;
    int t = threadIdx.x;
    const int PER = (L_ + 255) / 256;   // 7
    int base = t * PER;
    int c = 0;
    for (int j = 0; j < PER; ++j) {
        int l = base + j;
        if (l < L_ && active[b * L_ + l]) ++c;
    }
    cnt[t] = c;
    __syncthreads();
    for (int off = 1; off < 256; off <<= 1) {
        int v = (t >= off) ? cnt[t - off] : 0;
        __syncthreads();
        cnt[t] += v;
        __syncthreads();
    }
    int r = cnt[t] - c;   // exclusive prefix
    for (int j = 0; j < PER; ++j) {
        int l = base + j;
        if (l >= L_) break;
        if (active[b * L_ + l]) {
            RANK[b * L_ + l] = r;
            IDS[b * KEEP_ + r] = l;
            ++r;
        } else {
            RANK[b * L_ + l] = -1;
        }
    }
}

// X[b,i,c] = imgs[b,c,ids[b,i]] + pos[ids[b,i], c]
__global__ void gather_embed_k(const float* __restrict__ imgs,
                               const float* __restrict__ pos,
                               const int* __restrict__ IDS,
                               float* __restrict__ X) {
    int tid = blockIdx.x * 256 + threadIdx.x;
    if (tid >= B_ * KEEP_ * DM_) return;
    int c = tid % DM_;
    int i = (tid / DM_) % KEEP_;
    int b = tid / (DM_ * KEEP_);
    int l = IDS[b * KEEP_ + i];
    X[tid] = imgs[((size_t)b * DM_ + c) * L_ + l] + pos[(size_t)l * DM_ + c];
}

// out[b,c,l] = active ? X[b, rank, c] : mask_token[c]
__global__ void final_scatter_k(const float* __restrict__ X,
                                const float* __restrict__ mask_token,
                                const int* __restrict__ RANK,
                                float* __restrict__ out) {
    int tid = blockIdx.x * 256 + threadIdx.x;
    if (tid >= B_ * DM_ * L_) return;
    int l = tid % L_;
    int c = (tid / L_) % DM_;
    int b = tid / (L_ * DM_);
    int r = RANK[b * L_ + l];
    out[tid] = (r >= 0) ? X[((size_t)b * KEEP_ + r) * DM_ + c] : mask_token[c];
}

// ---------------------------------------------------------------- layernorm
// fp32 in -> bf16 out (GEMM A-input format)
__global__ void layernorm_k(const float* __restrict__ X,
                            const float* __restrict__ w,
                            const float* __restrict__ bia,
                            unsigned short* __restrict__ H, int rows) {
    int row = blockIdx.x * 4 + (threadIdx.x >> 6);
    int lane = threadIdx.x & 63;
    if (row >= rows) return;
    const float* x = X + (size_t)row * DM_;
    float v[6];
    float s = 0.0f;
#pragma unroll
    for (int j = 0; j < 6; ++j) { v[j] = x[lane + 64 * j]; s += v[j]; }
#pragma unroll
    for (int m = 1; m < 64; m <<= 1) s += __shfl_xor(s, m);
    float mu = s * (1.0f / DM_);
    float s2 = 0.0f;
#pragma unroll
    for (int j = 0; j < 6; ++j) { float d = v[j] - mu; s2 += d * d; }
#pragma unroll
    for (int m = 1; m < 64; m <<= 1) s2 += __shfl_xor(s2, m);
    float rs = rsqrtf(s2 * (1.0f / DM_) + 1e-5f);
    unsigned short* h = H + (size_t)row * DM_;
#pragma unroll
    for (int j = 0; j < 6; ++j) {
        int c = lane + 64 * j;
        h[c] = f2bf((v[j] - mu) * rs * w[c] + bia[c]);
    }
}

// ---------------------------------------------------------------- MFMA GEMM
// C[m,n] = sum_k (A[m,k] (+ A2[m,k])) * W[n,k]. abf16: A is bf16 and staged
// via global_load_lds; B always staged via global_load_lds (lane-linear
// [64][32] LDS tiles). fp32 A (out_proj sum) staged via registers.
// modes: 0 write fp32, 6 atomicAdd, 7 atomicAdd + bias on z==0,
//        9 bias+gelu -> bf16 write (C is ushort*)
#define APAD_ 32
__global__ __launch_bounds__(256) void gemm_mfma_k(
    const void* __restrict__ Ap, const float* __restrict__ A2, int lda,
    int abf16,
    const unsigned short* __restrict__ Wb,
    const float* __restrict__ bias,
    float* __restrict__ C, int ldc,
    int M, int N, int K, int kslices, int mode) {
    __shared__ unsigned short As[2][64][APAD_];
    __shared__ unsigned short Bs[2][64][APAD_];
    int t = threadIdx.x;
    int wave = t >> 6;
    int lane = t & 63;
    int q = lane >> 4;
    int ml = lane & 15;
    int m0 = blockIdx.y * 64;
    int n0 = blockIdx.x * 64;
    int z  = blockIdx.z;
    int Kper = K / kslices;
    int kbeg = z * Kper;

    int srow = t >> 2;          // staging row 0..63 == wave*16 + (lane>>2)
    int scol = (t & 3) * 8;     // staging col 0,8,16,24

    floatx4 acc[4];
#pragma unroll
    for (int i = 0; i < 4; ++i) acc[i] = (floatx4){0.f, 0.f, 0.f, 0.f};

    float ra[8];

    auto asyncB = [&](int k0, int buf) {
        gld_lds16(Wb + (size_t)(n0 + srow) * K + k0 + scol,
                  &Bs[buf][wave * 16][0]);
    };
    auto asyncA = [&](int k0, int buf) {
        gld_lds16((const unsigned short*)Ap + (size_t)(m0 + srow) * lda + k0 + scol,
                  &As[buf][wave * 16][0]);
    };
    auto loadA = [&](int k0) {   // fp32 (+A2) path
        const float* ap = (const float*)Ap + (size_t)(m0 + srow) * lda + k0 + scol;
        floatx4 v0 = *(const floatx4*)ap;
        floatx4 v1 = *(const floatx4*)(ap + 4);
        if (A2) {
            const float* ap2 = A2 + (size_t)(m0 + srow) * lda + k0 + scol;
            v0 += *(const floatx4*)ap2;
            v1 += *(const floatx4*)(ap2 + 4);
        }
#pragma unroll
        for (int j = 0; j < 4; ++j) { ra[j] = v0[j]; ra[4 + j] = v1[j]; }
    };
    auto storeA = [&](int buf) {
#pragma unroll
        for (int j = 0; j < 8; ++j) As[buf][srow][scol + j] = f2bf(ra[j]);
    };

    int nk = Kper >> 5;
    asyncB(kbeg, 0);
    if (abf16) { asyncA(kbeg, 0); }
    else       { loadA(kbeg); storeA(0); }
    __syncthreads();
    int buf = 0;
    for (int it = 0; it < nk; ++it) {
        if (it + 1 < nk) {
            int kn = kbeg + (it + 1) * 32;
            asyncB(kn, buf ^ 1);
            if (abf16) asyncA(kn, buf ^ 1);
            else       loadA(kn);
        }
        short8 a = *(const short8*)&As[buf][wave * 16 + ml][q * 8];
#pragma unroll
        for (int ns = 0; ns < 4; ++ns) {
            short8 b = *(const short8*)&Bs[buf][ns * 16 + ml][q * 8];
            acc[ns] = __builtin_amdgcn_mfma_f32_16x16x32_bf16(a, b, acc[ns], 0, 0, 0);
        }
        if (it + 1 < nk) {
            if (!abf16) storeA(buf ^ 1);
            __syncthreads();
            buf ^= 1;
        }
    }

    // ---- epilogue
#pragma unroll
    for (int ns = 0; ns < 4; ++ns) {
        int n = n0 + ns * 16 + ml;
#pragma unroll
        for (int r = 0; r < 4; ++r) {
            int m = m0 + wave * 16 + q * 4 + r;
            float v = acc[ns][r];
            size_t ci = (size_t)m * ldc + n;
            if (mode == 6) {
                atomicAdd(&C[ci], v);
            } else if (mode == 7) {
                if (z == 0) v += bias[n];
                atomicAdd(&C[ci], v);
            } else if (mode == 9) {
                ((unsigned short*)C)[ci] = f2bf(gelu_exact_f(v + bias[n]));
            } else {
                C[ci] = v;
            }
        }
    }
}

// ---------------------------------------------------------------- x_proj
// conv+silu fused into A staging (registers). B via global_load_lds
// (rows >= 56 read in-bounds garbage from WB; those columns are discarded
// in the epilogue so they never contaminate kept outputs).
// M=3456, N=56, K=768, split-K=XSPLIT_ slabs.
__global__ __launch_bounds__(256) void xproj_conv_k(
        const float* __restrict__ XZ,
        const float* __restrict__ cw,
        const float* __restrict__ cb,
        const unsigned short* __restrict__ Wb,   // xpw bf16 [56][768]
        float* __restrict__ Cout) {
    __shared__ unsigned short As[2][64][APAD_];
    __shared__ unsigned short Bs[2][64][APAD_];
    int t = threadIdx.x;
    int wave = t >> 6;
    int lane = t & 63;
    int q = lane >> 4;
    int ml = lane & 15;
    int m0 = blockIdx.y * 64;
    int z  = blockIdx.z;
    const int Kper = DI_ / XSPLIT_;   // 96
    int kbeg = z * Kper;
    float* C = Cout + (size_t)z * (2 * B_ * KEEP_) * XPR_;

    int srow = t >> 2;
    int scol = (t & 3) * 8;
    int m = m0 + srow;
    int dir = m / (B_ * KEEP_);
    int rem = m - dir * (B_ * KEEP_);
    int b = rem / KEEP_;
    int s = rem - b * KEEP_;

    floatx4 acc[4];
#pragma unroll
    for (int i = 0; i < 4; ++i) acc[i] = (floatx4){0.f, 0.f, 0.f, 0.f};

    float ra[8];

    auto asyncB = [&](int k0, int buf) {
        gld_lds16(Wb + (size_t)srow * DI_ + k0 + scol,
                  &Bs[buf][wave * 16][0]);
    };
    auto loadA = [&](int k0) {
        int d0 = k0 + scol;
        float v[8];
        {
            floatx4 c0v = *(const floatx4*)(cb + d0);
            floatx4 c1v = *(const floatx4*)(cb + d0 + 4);
#pragma unroll
            for (int j = 0; j < 4; ++j) { v[j] = c0v[j]; v[4 + j] = c1v[j]; }
        }
        float cwv[8][4];
#pragma unroll
        for (int jj = 0; jj < 8; ++jj) {
            floatx4 cv = *(const floatx4*)(cw + (size_t)(d0 + jj) * 4);
#pragma unroll
            for (int j = 0; j < 4; ++j) cwv[jj][j] = cv[j];
        }
#pragma unroll
        for (int j = 0; j < DC_; ++j) {
            int pos = s - (DC_ - 1) + j;
            if (pos >= 0) {
                int la = dir ? (KEEP_ - 1 - pos) : pos;
                const float* xp = XZ + ((size_t)b * KEEP_ + la) * (2 * DI_) + d0;
                floatx4 x0 = *(const floatx4*)xp;
                floatx4 x1 = *(const floatx4*)(xp + 4);
#pragma unroll
                for (int jj = 0; jj < 4; ++jj) v[jj] += cwv[jj][j] * x0[jj];
#pragma unroll
                for (int jj = 0; jj < 4; ++jj) v[4 + jj] += cwv[4 + jj][j] * x1[jj];
            }
        }
#pragma unroll
        for (int jj = 0; jj < 8; ++jj) ra[jj] = silu_f(v[jj]);
    };
    auto storeA = [&](int buf) {
#pragma unroll
        for (int j = 0; j < 8; ++j) As[buf][srow][scol + j] = f2bf(ra[j]);
    };

    const int nk = Kper >> 5;   // 3
    asyncB(kbeg, 0);
    loadA(kbeg);
    storeA(0);
    __syncthreads();
    int buf = 0;
    for (int it = 0; it < nk; ++it) {
        if (it + 1 < nk) {
            int kn = kbeg + (it + 1) * 32;
            asyncB(kn, buf ^ 1);
            loadA(kn);
        }
        short8 a = *(const short8*)&As[buf][wave * 16 + ml][q * 8];
#pragma unroll
        for (int ns = 0; ns < 4; ++ns) {
            short8 b2 = *(const short8*)&Bs[buf][ns * 16 + ml][q * 8];
            acc[ns] = __builtin_amdgcn_mfma_f32_16x16x32_bf16(a, b2, acc[ns], 0, 0, 0);
        }
        if (it + 1 < nk) {
            storeA(buf ^ 1);
            __syncthreads();
            buf ^= 1;
        }
    }
#pragma unroll
    for (int ns = 0; ns < 4; ++ns) {
        int n = ns * 16 + ml;
        if (n >= XPR_) continue;
#pragma unroll
        for (int r = 0; r < 4; ++r) {
            int mm = m0 + wave * 16 + q * 4 + r;
            C[(size_t)mm * XPR_ + n] = acc[ns][r];
        }
    }
}

// ---------------------------------------------------------------- SSM scan
// R10-verbatim (NC=48, CL=9, 3 separate kernels, geometric trick) —
// measured absmax 0.03125. Cooperative fusion of these phases is known-bad
// (R8/R9/R11: stale cross-block reads through grid.sync, G16).
#define PSL_ ((size_t)(2 * B_ * KEEP_) * XPR_)   // x_proj slab stride

__device__ __forceinline__ bool a_geometric(const float* alog, int d, float& Av0) {
    Av0 = -__expf(alog[(size_t)d * NS_]);
    bool fast = true;
#pragma unroll
    for (int n = 1; n < NS_; ++n) {
        float av = -__expf(alog[(size_t)d * NS_ + n]);
        float ref = (float)(n + 1) * Av0;
        fast = fast && (fabsf(av - ref) <= 1e-4f * fabsf(ref));
    }
    return fast;
}

// Phase A: block = (dgroup of 256, chunk, b, dir). h[16] in registers.
__global__ __launch_bounds__(256) void scan_partial_k(
        const float* __restrict__ XZ,
        const float* __restrict__ PART,
        const float* __restrict__ cw,
        const float* __restrict__ cb,
        const float* __restrict__ dtw,
        const float* __restrict__ dtb,
        const float* __restrict__ Alog,
        const float* __restrict__ Ablog,
        float* __restrict__ HS,
        float* __restrict__ SDELT) {
    __shared__ float sXDB[CL_][XPR_];
    int blk = blockIdx.x;
    int g   = blk % 3;
    int c   = (blk / 3) % NC_;
    int b   = (blk / (3 * NC_)) % B_;
    int dir = blk / (3 * NC_ * B_);
    int t = threadIdx.x;
    int d = g * 256 + t;
    int c0 = c * CL_;
    int dirb = dir * B_ + b;

    size_t rbase = ((size_t)dirb * KEEP_ + c0) * XPR_;
    for (int i = t; i < CL_ * XPR_; i += 256) {
        size_t idx = rbase + i;
        float v = PART[idx];
#pragma unroll
        for (int sl = 1; sl < XSPLIT_; ++sl) v += PART[idx + sl * PSL_];
        sXDB[i / XPR_][i % XPR_] = v;
    }
    __syncthreads();

    floatx4 cwv = *(const floatx4*)(cw + (size_t)d * 4);
    float cbv = cb[d];
    float dtwv[DTR_];
#pragma unroll
    for (int r = 0; r < DTR_ / 4; ++r) {
        floatx4 v = *(const floatx4*)(dtw + (size_t)d * DTR_ + r * 4);
#pragma unroll
        for (int j = 0; j < 4; ++j) dtwv[r * 4 + j] = v[j];
    }
    float dtbv = dtb[d];
    const float* alog = dir ? Ablog : Alog;
    float Av0;
    bool fast = a_geometric(alog, d, Av0);

    auto xr_at = [&](int pos) -> float {
        if (pos < 0) return 0.0f;
        int la = dir ? (KEEP_ - 1 - pos) : pos;
        return XZ[((size_t)b * KEEP_ + la) * (2 * DI_) + d];
    };
    float w0 = xr_at(c0 - 3), w1 = xr_at(c0 - 2), w2 = xr_at(c0 - 1);

    float h[NS_];
#pragma unroll
    for (int n = 0; n < NS_; ++n) h[n] = 0.0f;
    float sdel = 0.0f;

    if (fast) {
#pragma unroll
        for (int s = 0; s < CL_; ++s) {
            float w3 = xr_at(c0 + s);
            float xv = silu_f(cbv + cwv[0] * w0 + cwv[1] * w1 + cwv[2] * w2 + cwv[3] * w3);
            w0 = w1; w1 = w2; w2 = w3;
            float dt = dtbv;
#pragma unroll
            for (int r = 0; r < DTR_; ++r) dt += dtwv[r] * sXDB[s][r];
            dt = softplus_f(dt);
            sdel += dt;
            float dx = dt * xv;
            float e1 = __expf(dt * Av0);
            float e = e1;
#pragma unroll
            for (int n = 0; n < NS_; ++n) {
                h[n] = e * h[n] + dx * sXDB[s][DTR_ + n];
                e *= e1;
            }
        }
    } else {
        for (int s = 0; s < CL_; ++s) {
            float w3 = xr_at(c0 + s);
            float xv = silu_f(cbv + cwv[0] * w0 + cwv[1] * w1 + cwv[2] * w2 + cwv[3] * w3);
            w0 = w1; w1 = w2; w2 = w3;
            float dt = dtbv;
            for (int r = 0; r < DTR_; ++r) dt += dtwv[r] * sXDB[s][r];
            dt = softplus_f(dt);
            sdel += dt;
            float dx = dt * xv;
            for (int n = 0; n < NS_; ++n) {
                float av = -__expf(alog[(size_t)d * NS_ + n]);
                h[n] = __expf(dt * av) * h[n] + dx * sXDB[s][DTR_ + n];
            }
        }
    }
    size_t ob = ((size_t)dirb * NC_ + c) * NS_;
    SDELT[((size_t)dirb * NC_ + c) * DI_ + d] = sdel;
#pragma unroll
    for (int n = 0; n < NS_; ++n) HS[(ob + n) * DI_ + d] = h[n];
}

// Phase B: thread = (dir,b,d,n); serial combine across chunks, in-place on HS.
__global__ __launch_bounds__(256) void scan_combine_k(
        float* __restrict__ HS,
        const float* __restrict__ SDELT,
        const float* __restrict__ Alog,
        const float* __restrict__ Ablog) {
    int gid = blockIdx.x * 256 + threadIdx.x;
    int d = gid % DI_;
    int n = (gid / DI_) % NS_;
    int b = (gid / (DI_ * NS_)) % B_;
    int dir = gid / (DI_ * NS_ * B_);
    int dirb = dir * B_ + b;
    const float* alog = dir ? Ablog : Alog;
    float Av = -__expf(alog[(size_t)d * NS_ + n]);
    float hi = 0.0f;
    size_t sbase = (size_t)dirb * NC_ * DI_ + d;
    size_t hbase = ((size_t)dirb * NC_ * NS_ + n) * DI_ + d;
    float sd_n = SDELT[sbase];
    float hf_n = HS[hbase];
    for (int c = 0; c < NC_; ++c) {
        float sd = sd_n, hf = hf_n;
        if (c + 1 < NC_) {
            sd_n = SDELT[sbase + (size_t)(c + 1) * DI_];
            hf_n = HS[hbase + (size_t)(c + 1) * NS_ * DI_];
        }
        HS[hbase + (size_t)c * NS_ * DI_] = hi;
        hi = __expf(Av * sd) * hi + hf;
    }
}

// Phase C: replay with h_init; y = sum_n h*C; gate with silu(z); write YOUT.
__global__ __launch_bounds__(256) void scan_final_k(
        const float* __restrict__ XZ,
        const float* __restrict__ PART,
        const float* __restrict__ cw,
        const float* __restrict__ cb,
        const float* __restrict__ dtw,
        const float* __restrict__ dtb,
        const float* __restrict__ Alog,
        const float* __restrict__ Ablog,
        const float* __restrict__ dskip,
        const float* __restrict__ HS,
        float* __restrict__ YOUT) {
    __shared__ float sXDB[CL_][XPR_];
    int blk = blockIdx.x;
    int g   = blk % 3;
    int c   = (blk / 3) % NC_;
    int b   = (blk / (3 * NC_)) % B_;
    int dir = blk / (3 * NC_ * B_);
    int t = threadIdx.x;
    int d = g * 256 + t;
    int c0 = c * CL_;
    int dirb = dir * B_ + b;

    size_t rbase = ((size_t)dirb * KEEP_ + c0) * XPR_;
    for (int i = t; i < CL_ * XPR_; i += 256) {
        size_t idx = rbase + i;
        float v = PART[idx];
#pragma unroll
        for (int sl = 1; sl < XSPLIT_; ++sl) v += PART[idx + sl * PSL_];
        sXDB[i / XPR_][i % XPR_] = v;
    }
    __syncthreads();

    floatx4 cwv = *(const floatx4*)(cw + (size_t)d * 4);
    float cbv = cb[d];
    float dtwv[DTR_];
#pragma unroll
    for (int r = 0; r < DTR_ / 4; ++r) {
        floatx4 v = *(const floatx4*)(dtw + (size_t)d * DTR_ + r * 4);
#pragma unroll
        for (int j = 0; j < 4; ++j) dtwv[r * 4 + j] = v[j];
    }
    float dtbv = dtb[d];
    const float* alog = dir ? Ablog : Alog;
    float Av0;
    bool fast = a_geometric(alog, d, Av0);
    float dsk = dskip[d];

    float h[NS_];
    size_t hbase = ((size_t)dirb * NC_ + c) * NS_;
#pragma unroll
    for (int n = 0; n < NS_; ++n) h[n] = HS[(hbase + n) * DI_ + d];

    auto xr_at = [&](int pos) -> float {
        if (pos < 0) return 0.0f;
        int la = dir ? (KEEP_ - 1 - pos) : pos;
        return XZ[((size_t)b * KEEP_ + la) * (2 * DI_) + d];
    };
    float w0 = xr_at(c0 - 3), w1 = xr_at(c0 - 2), w2 = xr_at(c0 - 1);

    if (fast) {
#pragma unroll
        for (int s = 0; s < CL_; ++s) {
            int pos = c0 + s;
            int la = dir ? (KEEP_ - 1 - pos) : pos;
            float w3 = XZ[((size_t)b * KEEP_ + la) * (2 * DI_) + d];
            float zg = XZ[((size_t)b * KEEP_ + la) * (2 * DI_) + DI_ + d];
            float xv = silu_f(cbv + cwv[0] * w0 + cwv[1] * w1 + cwv[2] * w2 + cwv[3] * w3);
            w0 = w1; w1 = w2; w2 = w3;
            float dt = dtbv;
#pragma unroll
            for (int r = 0; r < DTR_; ++r) dt += dtwv[r] * sXDB[s][r];
            dt = softplus_f(dt);
            float dx = dt * xv;
            float e1 = __expf(dt * Av0);
            float e = e1;
            float y = 0.0f;
#pragma unroll
            for (int n = 0; n < NS_; ++n) {
                h[n] = e * h[n] + dx * sXDB[s][DTR_ + n];
                y += h[n] * sXDB[s][DTR_ + NS_ + n];
                e *= e1;
            }
            YOUT[((size_t)dirb * KEEP_ + la) * DI_ + d] =
                (y + dsk * xv) * silu_f(zg);
        }
    } else {
        for (int s = 0; s < CL_; ++s) {
            int pos = c0 + s;
            int la = dir ? (KEEP_ - 1 - pos) : pos;
            float w3 = XZ[((size_t)b * KEEP_ + la) * (2 * DI_) + d];
            float zg = XZ[((size_t)b * KEEP_ + la) * (2 * DI_) + DI_ + d];
            float xv = silu_f(cbv + cwv[0] * w0 + cwv[1] * w1 + cwv[2] * w2 + cwv[3] * w3);
            w0 = w1; w1 = w2; w2 = w3;
            float dt = dtbv;
            for (int r = 0; r < DTR_; ++r) dt += dtwv[r] * sXDB[s][r];
            dt = softplus_f(dt);
            float dx = dt * xv;
            float y = 0.0f;
            for (int n = 0; n < NS_; ++n) {
                float av = -__expf(alog[(size_t)d * NS_ + n]);
                h[n] = __expf(dt * av) * h[n] + dx * sXDB[s][DTR_ + n];
                y += h[n] * sXDB[s][DTR_ + NS_ + n];
            }
            YOUT[((size_t)dirb * KEEP_ + la) * DI_ + d] =
                (y + dsk * xv) * silu_f(zg);
        }
    }
}

// ---------------------------------------------------------------- launcher
extern "C" void kernel_launch(void* const* d_in, const int* in_sizes, int n_in,
                              void* d_out, int out_size, void* d_ws, size_t ws_size,
                              hipStream_t stream) {
    const float* imgs      = (const float*)d_in[0];
    const float* pos       = (const float*)d_in[1];
    const float* mask_tok  = (const float*)d_in[2];
    const float* n1w       = (const float*)d_in[3];
    const float* n1b       = (const float*)d_in[4];
    const float* inW       = (const float*)d_in[5];
    const float* cw        = (const float*)d_in[6];
    const float* cb        = (const float*)d_in[7];
    const float* xpw       = (const float*)d_in[8];
    const float* dtw       = (const float*)d_in[9];
    const float* dtb       = (const float*)d_in[10];
    const float* Alog      = (const float*)d_in[11];
    const float* Ablog     = (const float*)d_in[12];
    const float* dskip     = (const float*)d_in[13];
    const float* ow        = (const float*)d_in[14];
    const float* n2w       = (const float*)d_in[15];
    const float* n2b       = (const float*)d_in[16];
    const float* f1w       = (const float*)d_in[17];
    const float* f1b       = (const float*)d_in[18];
    const float* f2w       = (const float*)d_in[19];
    const float* f2b       = (const float*)d_in[20];
    const int*   active    = (const int*)d_in[21];
    float* out = (float*)d_out;

    // workspace carve
    char* w = (char*)d_ws;
    auto alloc = [&](size_t bytes) {
        void* p = (void*)w;
        w += (bytes + 255) & ~(size_t)255;
        return p;
    };
    int*   RANK  = (int*)  alloc((size_t)B_ * L_ * 4);
    int*   IDS   = (int*)  alloc((size_t)B_ * KEEP_ * 4);
    float* X     = (float*)alloc((size_t)B_ * KEEP_ * DM_ * 4);
    unsigned short* Hb = (unsigned short*)alloc((size_t)B_ * KEEP_ * DM_ * 2);
    float* XZ    = (float*)alloc((size_t)B_ * KEEP_ * 2 * DI_ * 4);
    float* PART  = (float*)alloc((size_t)XSPLIT_ * 2 * B_ * KEEP_ * XPR_ * 4);
    float* YOUT  = (float*)alloc((size_t)2 * B_ * KEEP_ * DI_ * 4);
    unsigned short* Gb = (unsigned short*)alloc((size_t)B_ * KEEP_ * DI_ * 2);
    float* HS    = (float*)alloc((size_t)2 * B_ * NC_ * NS_ * DI_ * 4);
    float* SDELT = (float*)alloc((size_t)2 * B_ * NC_ * DI_ * 4);
    unsigned short* WB = (unsigned short*)alloc((size_t)WTOT_ * 2);

    const unsigned short* wInB = WB;
    const unsigned short* wXpB = WB + S0_;
    const unsigned short* wOwB = WB + S0_ + S1_;
    const unsigned short* wF1B = WB + S0_ + S1_ + S3_;
    const unsigned short* wF2B = WB + S0_ + S1_ + S3_ + S4_;

    const int ROWS = B_ * KEEP_;       // 1728
    const int ROWS2 = 2 * B_ * KEEP_;  // 3456
    const int SCAN_BLOCKS = 2 * B_ * NC_ * 3;   // 1152

    cast_weights_k<<<(WTOT_ + 255) / 256, 256, 0, stream>>>(
        inW, xpw, ow, f1w, f2w, (unsigned short*)WB);
    compute_ids_k<<<B_, 256, 0, stream>>>(active, RANK, IDS);
    gather_embed_k<<<(B_ * KEEP_ * DM_ + 255) / 256, 256, 0, stream>>>(imgs, pos, IDS, X);

    for (int layer = 0; layer < DEPTH_; ++layer) {
        const unsigned short* L_inW = wInB + (size_t)layer * 2 * DI_ * DM_;
        const float* L_cw  = cw  + (size_t)layer * DI_ * DC_;
        const float* L_cb  = cb  + (size_t)layer * DI_;
        const unsigned short* L_xpw = wXpB + (size_t)layer * XPR_ * DI_;
        const float* L_dtw = dtw + (size_t)layer * DI_ * DTR_;
        const float* L_dtb = dtb + (size_t)layer * DI_;
        const float* L_Al  = Alog  + (size_t)layer * DI_ * NS_;
        const float* L_Abl = Ablog + (size_t)layer * DI_ * NS_;
        const float* L_dsk = dskip + (size_t)layer * DI_;
        const unsigned short* L_ow  = wOwB + (size_t)layer * DM_ * DI_;
        const unsigned short* L_f1w = wF1B + (size_t)layer * 2 * DM_ * DM_;
        const float* L_f1b = f1b + (size_t)layer * 2 * DM_;
        const unsigned short* L_f2w = wF2B + (size_t)layer * DM_ * 2 * DM_;
        const float* L_f2b = f2b + (size_t)layer * DM_;

        // LN1 -> bf16 H
        layernorm_k<<<(ROWS + 3) / 4, 256, 0, stream>>>(
            X, n1w + layer * DM_, n1b + layer * DM_, Hb, ROWS);
        // in_proj: (1728x384)bf16 x (1536x384)^T -> XZ fp32
        gemm_mfma_k<<<dim3((2 * DI_) / 64, ROWS / 64), 256, 0, stream>>>(
            Hb, nullptr, DM_, 1, L_inW, nullptr, XZ, 2 * DI_,
            ROWS, 2 * DI_, DM_, 1, 0);
        // x_proj with fused conv+silu, split-K=8 -> PART slabs
        xproj_conv_k<<<dim3(1, ROWS2 / 64, XSPLIT_), 256, 0, stream>>>(
            XZ, L_cw, L_cb, L_xpw, PART);
        // fused scan (conv + dt-proj in-kernel), 3 phases — R10 config
        scan_partial_k<<<SCAN_BLOCKS, 256, 0, stream>>>(
            XZ, PART, L_cw, L_cb, L_dtw, L_dtb, L_Al, L_Abl, HS, SDELT);
        scan_combine_k<<<(2 * B_ * NS_ * DI_) / 256, 256, 0, stream>>>(
            HS, SDELT, L_Al, L_Abl);
        scan_final_k<<<SCAN_BLOCKS, 256, 0, stream>>>(
            XZ, PART, L_cw, L_cb, L_dtw, L_dtb, L_Al, L_Abl, L_dsk, HS, YOUT);
        // out_proj split-K=4, atomic residual into X
        gemm_mfma_k<<<dim3(DM_ / 64, ROWS / 64, 4), 256, 0, stream>>>(
            YOUT, YOUT + (size_t)B_ * KEEP_ * DI_, DI_, 0, L_ow, nullptr,
            X, DM_, ROWS, DM_, DI_, 4, 6);
        // LN2 -> bf16 H
        layernorm_k<<<(ROWS + 3) / 4, 256, 0, stream>>>(
            X, n2w + layer * DM_, n2b + layer * DM_, Hb, ROWS);
        // fc1 + bias + gelu -> bf16 G
        gemm_mfma_k<<<dim3((2 * DM_) / 64, ROWS / 64), 256, 0, stream>>>(
            Hb, nullptr, DM_, 1, L_f1w, L_f1b, (float*)Gb, 2 * DM_,
            ROWS, 2 * DM_, DM_, 1, 9);
        // fc2 split-K=4, atomic + bias(z0) + residual into X
        gemm_mfma_k<<<dim3(DM_ / 64, ROWS / 64, 4), 256, 0, stream>>>(
            Gb, nullptr, 2 * DM_, 1, L_f2w, L_f2b, X, DM_,
            ROWS, DM_, 2 * DM_, 4, 7);
    }

    final_scatter_k<<<(B_ * DM_ * L_ + 255) / 256, 256, 0, stream>>>(
        X, mask_tok, RANK, out);
}